// Round 1
// baseline (564.718 us; speedup 1.0000x reference)
//
#include <hip/hip_runtime.h>

#define T_STEPS 2048
#define B_CH    8192
#define TILE    16
#define DT_F    0.01f

// fast HW instructions: v_rsq_f32, v_log_f32 (log2)
__device__ __forceinline__ float fast_rsqrt(float x) { return __builtin_amdgcn_rsqf(x); }
__device__ __forceinline__ float fast_log2(float x)  { return __builtin_amdgcn_logf(x); }

struct Q9 {
  float q00, q01, q02, q10, q11, q12, q20, q21, q22;
};

// One reference-faithful step: M = (I + DT*J(x,y,z)) * Q, row Gram-Schmidt,
// accumulate log2(norm^2) per row (scaled by 0.5*ln2/(T*DT) at the end).
__device__ __forceinline__ void gs_step(float x, float y, float z, Q9& Q,
                                        float& S0, float& S1, float& S2) {
  // A = I + DT*J ; J = [[-s, s, 0], [r - z, -1, -x], [y, x, -b]]
  const float a00 = 1.0f - DT_F * 10.0f;          // 0.9
  const float a01 = DT_F * 10.0f;                 // 0.1
  const float a11 = 1.0f - DT_F;                  // 0.99
  const float a22 = 1.0f - DT_F * (8.0f / 3.0f);
  float a10 = DT_F * (28.0f - z);
  float a12 = -DT_F * x;
  float a20 = DT_F * y;
  float a21 = DT_F * x;

  // M = A * Q (row i of M = sum_j A[i][j] * row j of Q); A[0][2] == 0
  float m00 = a00 * Q.q00 + a01 * Q.q10;
  float m01 = a00 * Q.q01 + a01 * Q.q11;
  float m02 = a00 * Q.q02 + a01 * Q.q12;
  float m10 = a10 * Q.q00 + a11 * Q.q10 + a12 * Q.q20;
  float m11 = a10 * Q.q01 + a11 * Q.q11 + a12 * Q.q21;
  float m12 = a10 * Q.q02 + a11 * Q.q12 + a12 * Q.q22;
  float m20 = a20 * Q.q00 + a21 * Q.q10 + a22 * Q.q20;
  float m21 = a20 * Q.q01 + a21 * Q.q11 + a22 * Q.q21;
  float m22 = a20 * Q.q02 + a21 * Q.q12 + a22 * Q.q22;

  // row 0
  float n0 = m00 * m00 + m01 * m01 + m02 * m02;
  float i0 = fast_rsqrt(n0);
  Q.q00 = m00 * i0; Q.q01 = m01 * i0; Q.q02 = m02 * i0;
  S0 += fast_log2(n0);

  // row 1: subtract projection onto q0
  float d1 = Q.q00 * m10 + Q.q01 * m11 + Q.q02 * m12;
  float r10 = m10 - d1 * Q.q00;
  float r11 = m11 - d1 * Q.q01;
  float r12 = m12 - d1 * Q.q02;
  float n1 = r10 * r10 + r11 * r11 + r12 * r12;
  float i1 = fast_rsqrt(n1);
  Q.q10 = r10 * i1; Q.q11 = r11 * i1; Q.q12 = r12 * i1;
  S1 += fast_log2(n1);

  // row 2: sequential projections (reference order: uses updated r for 2nd dot)
  float d2 = Q.q00 * m20 + Q.q01 * m21 + Q.q02 * m22;
  float r20 = m20 - d2 * Q.q00;
  float r21 = m21 - d2 * Q.q01;
  float r22 = m22 - d2 * Q.q02;
  float d3 = Q.q10 * r20 + Q.q11 * r21 + Q.q12 * r22;
  r20 -= d3 * Q.q10;
  r21 -= d3 * Q.q11;
  r22 -= d3 * Q.q12;
  float n2 = r20 * r20 + r21 * r21 + r22 * r22;
  float i2 = fast_rsqrt(n2);
  Q.q20 = r20 * i2; Q.q21 = r21 * i2; Q.q22 = r22 * i2;
  S2 += fast_log2(n2);
}

// One thread per chain. 128 blocks x 64 threads = 8192 threads = 128 waves,
// 1 wave per block so waves spread across 128 CUs. Ping-pong register staging
// of TILE timesteps (48 coalesced dword loads issued a full tile ahead of use:
// prefetch distance ~16 steps * ~150 cyc >> 900 cyc HBM latency).
__global__ __launch_bounds__(64) void lyap_kernel(const float* __restrict__ traj,
                                                  float* __restrict__ out) {
  const int b = blockIdx.x * 64 + threadIdx.x;
  const float* __restrict__ p = traj + b;

  float sA[TILE][3], sB[TILE][3];

  // preload tile 0 into A
#pragma unroll
  for (int i = 0; i < TILE; ++i) {
    sA[i][0] = p[(size_t)(i * 3 + 0) * B_CH];
    sA[i][1] = p[(size_t)(i * 3 + 1) * B_CH];
    sA[i][2] = p[(size_t)(i * 3 + 2) * B_CH];
  }

  Q9 Q = {1.f, 0.f, 0.f, 0.f, 1.f, 0.f, 0.f, 0.f, 1.f};
  float S0 = 0.f, S1 = 0.f, S2 = 0.f;

  const int NTILES = T_STEPS / TILE;  // 128
  for (int tb = 0; tb < NTILES; tb += 2) {
    // issue loads for tile tb+1 into B (always valid: tb+1 <= 127)
    {
      const float* pB = p + (size_t)(tb + 1) * TILE * 3 * B_CH;
#pragma unroll
      for (int i = 0; i < TILE; ++i) {
        sB[i][0] = pB[(size_t)(i * 3 + 0) * B_CH];
        sB[i][1] = pB[(size_t)(i * 3 + 1) * B_CH];
        sB[i][2] = pB[(size_t)(i * 3 + 2) * B_CH];
      }
    }
    // compute tile tb from A
#pragma unroll
    for (int i = 0; i < TILE; ++i)
      gs_step(sA[i][0], sA[i][1], sA[i][2], Q, S0, S1, S2);

    // issue loads for tile tb+2 into A
    if (tb + 2 < NTILES) {
      const float* pA = p + (size_t)(tb + 2) * TILE * 3 * B_CH;
#pragma unroll
      for (int i = 0; i < TILE; ++i) {
        sA[i][0] = pA[(size_t)(i * 3 + 0) * B_CH];
        sA[i][1] = pA[(size_t)(i * 3 + 1) * B_CH];
        sA[i][2] = pA[(size_t)(i * 3 + 2) * B_CH];
      }
    }
    // compute tile tb+1 from B
#pragma unroll
    for (int i = 0; i < TILE; ++i)
      gs_step(sB[i][0], sB[i][1], sB[i][2], Q, S0, S1, S2);
  }

  // S holds sum of log2(n^2); lognorm sum = 0.5*ln2*S; divide by T*DT
  const float scale = 0.5f * 0.69314718055994531f / (T_STEPS * DT_F);
  out[0 * B_CH + b] = S0 * scale;
  out[1 * B_CH + b] = S1 * scale;
  out[2 * B_CH + b] = S2 * scale;
}

extern "C" void kernel_launch(void* const* d_in, const int* in_sizes, int n_in,
                              void* d_out, int out_size, void* d_ws, size_t ws_size,
                              hipStream_t stream) {
  (void)in_sizes; (void)n_in; (void)out_size; (void)d_ws; (void)ws_size;
  const float* traj = (const float*)d_in[0];
  float* out = (float*)d_out;
  lyap_kernel<<<dim3(B_CH / 64), dim3(64), 0, stream>>>(traj, out);
}

// Round 2
// 307.511 us; speedup vs baseline: 1.8364x; 1.8364x over previous
//
#include <hip/hip_runtime.h>

#define T_STEPS 2048
#define B_CH    8192
#define DT_F    0.01f
#define CHUNK   128            // steps accumulated per chunk
#define WARM    64             // warm-up steps (discarded) to converge Q
#define NCHUNK  (T_STEPS / CHUNK)   // 16
#define TILE    8              // register-staged timesteps per prefetch buffer

__device__ __forceinline__ float fast_rsqrt(float x) { return __builtin_amdgcn_rsqf(x); }
__device__ __forceinline__ float fast_log2(float x)  { return __builtin_amdgcn_logf(x); }

struct Q9 { float q00,q01,q02,q10,q11,q12,q20,q21,q22; };

// One step: M = (I + DT*J(x,y,z)) * Q, row Gram-Schmidt, accumulate log2(n^2).
// Restructured for short critical path: unnormalized projection dots (d1u,d2u
// computable in parallel with n0) and 1/n = rsq(n)^2 instead of normalized
// dots — removes two dependent dot products from the per-step latency chain.
__device__ __forceinline__ void gs_step(float x, float y, float z, Q9& Q,
                                        float& S0, float& S1, float& S2) {
  const float a00 = 0.9f;        // 1 - DT*SIGMA
  const float a01 = 0.1f;        // DT*SIGMA
  const float a11 = 0.99f;       // 1 - DT
  const float a22 = 1.0f - DT_F * (8.0f / 3.0f);
  float a10 = DT_F * (28.0f - z);
  float a12 = -DT_F * x;
  float a20 = DT_F * y;
  float a21 = DT_F * x;

  // M = A * Q  (A[0][2] == 0)
  float m00 = a00*Q.q00 + a01*Q.q10;
  float m01 = a00*Q.q01 + a01*Q.q11;
  float m02 = a00*Q.q02 + a01*Q.q12;
  float m10 = a10*Q.q00 + a11*Q.q10 + a12*Q.q20;
  float m11 = a10*Q.q01 + a11*Q.q11 + a12*Q.q21;
  float m12 = a10*Q.q02 + a11*Q.q12 + a12*Q.q22;
  float m20 = a20*Q.q00 + a21*Q.q10 + a22*Q.q20;
  float m21 = a20*Q.q01 + a21*Q.q11 + a22*Q.q21;
  float m22 = a20*Q.q02 + a21*Q.q12 + a22*Q.q22;

  // independent dots (all start as soon as M is ready)
  float n0  = m00*m00 + m01*m01 + m02*m02;
  float d1u = m00*m10 + m01*m11 + m02*m12;
  float d2u = m00*m20 + m01*m21 + m02*m22;

  float i0 = fast_rsqrt(n0);
  float inv0 = i0 * i0;
  S0 += fast_log2(n0);
  Q.q00 = m00*i0; Q.q01 = m01*i0; Q.q02 = m02*i0;   // off critical path

  float c1 = d1u * inv0;
  float r10 = m10 - c1*m00, r11 = m11 - c1*m01, r12 = m12 - c1*m02;
  float c2 = d2u * inv0;
  float r20 = m20 - c2*m00, r21 = m21 - c2*m01, r22 = m22 - c2*m02;

  float n1 = r10*r10 + r11*r11 + r12*r12;
  float i1 = fast_rsqrt(n1);
  float inv1 = i1 * i1;
  S1 += fast_log2(n1);
  Q.q10 = r10*i1; Q.q11 = r11*i1; Q.q12 = r12*i1;

  float d3u = r10*r20 + r11*r21 + r12*r22;
  float c3 = d3u * inv1;
  float s20 = r20 - c3*r10, s21 = r21 - c3*r11, s22 = r22 - c3*r12;
  float n2 = s20*s20 + s21*s21 + s22*s22;
  float i2 = fast_rsqrt(n2);
  S2 += fast_log2(n2);
  Q.q20 = s20*i2; Q.q21 = s21*i2; Q.q22 = s22*i2;
}

// Grid: (128, NCHUNK) blocks of 64. blockIdx.y = time chunk, one thread per
// chain. Each chunk warms up WARM steps from identity (Q forgets its initial
// condition at rate ~e^{-0.14/step}), snapshots the running log-sums at the
// chunk boundary, accumulates CHUNK steps, and writes (S - Ssnap) partials.
__global__ __launch_bounds__(64) void lyap_chunk_kernel(const float* __restrict__ traj,
                                                        float* __restrict__ ws) {
  const int b = blockIdx.x * 64 + threadIdx.x;       // chain id
  const int chunk = blockIdx.y;
  const int warm = (chunk == 0) ? 0 : WARM;
  const int warmTiles = warm / TILE;                 // 0 or 8
  const int ntiles = (CHUNK + warm) / TILE;          // 16 or 24 (even)
  const float* __restrict__ p =
      traj + (size_t)(chunk * CHUNK - warm) * (3 * B_CH) + b;

  float sA[TILE][3], sB[TILE][3];
#pragma unroll
  for (int i = 0; i < TILE; ++i) {
    sA[i][0] = p[(i*3 + 0) * B_CH];
    sA[i][1] = p[(i*3 + 1) * B_CH];
    sA[i][2] = p[(i*3 + 2) * B_CH];
  }

  Q9 Q = {1.f,0.f,0.f, 0.f,1.f,0.f, 0.f,0.f,1.f};
  float S0 = 0.f, S1 = 0.f, S2 = 0.f;
  float B0 = 0.f, B1 = 0.f, B2 = 0.f;                // snapshot at chunk start

  for (int t = 0; t < ntiles; t += 2) {
    {  // prefetch tile t+1 into B
      const float* pB = p + (size_t)(t + 1) * TILE * 3 * B_CH;
#pragma unroll
      for (int i = 0; i < TILE; ++i) {
        sB[i][0] = pB[(i*3 + 0) * B_CH];
        sB[i][1] = pB[(i*3 + 1) * B_CH];
        sB[i][2] = pB[(i*3 + 2) * B_CH];
      }
    }
    if (t == warmTiles) { B0 = S0; B1 = S1; B2 = S2; }  // warmTiles is even
#pragma unroll
    for (int i = 0; i < TILE; ++i)
      gs_step(sA[i][0], sA[i][1], sA[i][2], Q, S0, S1, S2);

    if (t + 2 < ntiles) {  // prefetch tile t+2 into A
      const float* pA = p + (size_t)(t + 2) * TILE * 3 * B_CH;
#pragma unroll
      for (int i = 0; i < TILE; ++i) {
        sA[i][0] = pA[(i*3 + 0) * B_CH];
        sA[i][1] = pA[(i*3 + 1) * B_CH];
        sA[i][2] = pA[(i*3 + 2) * B_CH];
      }
    }
#pragma unroll
    for (int i = 0; i < TILE; ++i)
      gs_step(sB[i][0], sB[i][1], sB[i][2], Q, S0, S1, S2);
  }

  ws[(chunk*3 + 0) * B_CH + b] = S0 - B0;
  ws[(chunk*3 + 1) * B_CH + b] = S1 - B1;
  ws[(chunk*3 + 2) * B_CH + b] = S2 - B2;
}

__global__ __launch_bounds__(256) void lyap_reduce_kernel(const float* __restrict__ ws,
                                                          float* __restrict__ out) {
  const int i = blockIdx.x * 256 + threadIdx.x;      // 0 .. 3*B_CH
  float s = 0.f;
#pragma unroll
  for (int c = 0; c < NCHUNK; ++c) s += ws[c * 3 * B_CH + i];
  const float scale = 0.5f * 0.69314718055994531f / (T_STEPS * DT_F);
  out[i] = s * scale;
}

extern "C" void kernel_launch(void* const* d_in, const int* in_sizes, int n_in,
                              void* d_out, int out_size, void* d_ws, size_t ws_size,
                              hipStream_t stream) {
  (void)in_sizes; (void)n_in; (void)out_size; (void)ws_size;
  const float* traj = (const float*)d_in[0];
  float* out = (float*)d_out;
  float* ws  = (float*)d_ws;   // needs NCHUNK*3*B_CH*4 = 1.57 MB

  lyap_chunk_kernel<<<dim3(B_CH / 64, NCHUNK), dim3(64), 0, stream>>>(traj, ws);
  lyap_reduce_kernel<<<dim3(3 * B_CH / 256), dim3(256), 0, stream>>>(ws, out);
}